// Round 12
// baseline (35.830 us; speedup 1.0000x reference)
//
#include <hip/hip_runtime.h>
#include <math.h>

// ---------------- workspace layout (float offsets) ----------------
#define WS_HXPART 0          // [(n*256+j)*4 + cb] : 4 k-chunks of x@g1_lin[:510]
#define WS_SMALL  8192       // contiguous small block, mirrored to k2 LDS
#define SM_XCNN 0            // 16
#define SM_SE1A 16           // 68 (e*4+hd; self-loop at 64+hd)
#define SM_SE1B 84           // 68
#define SM_SE2  152          // 17
#define SM_WF   172          // 1280
#define SM_BF   1452         // 10
#define SM_VME  1462         // 128: even mean 0-64, odd mean 64-128
#define SM_SIZE 1600

// ---------------- k2 LDS map (floats) ----------------
#define F_H    0      // 2048 (tail: rA dump region 0..7680; then u@4096, f@1024)
#define F_X1   2048   // 2048
#define F_H2P  4096   // 2048
#define F_GL0  6144   // 256
#define F_GL1  6400   // 256
#define F_G1AS 6656   // 256
#define F_G1AD 6912   // 256
#define F_G1B  7168   // 256
#define F_SS1  7424   // 32
#define F_SD1  7456   // 32
#define F_MX1  7488   // 32
#define F_DN1  7520   // 32
#define F_WT1  7552   // 96
#define F_SW2  7680   // 6144 (tail); front GAT2 regions reuse 7680..9728
#define F_A1   7680   // 256
#define F_H2   7936   // 512
#define F_X2   8448   // 512
#define F_G2AS 8960   // 64
#define F_G2AD 9024   // 64
#define F_G2B  9088   // 64
#define F_SS2  9152   // 8
#define F_SD2  9160   // 8
#define F_MX2  9168   // 8
#define F_DN2  9176   // 8
#define F_A2   9184   // 64
#define F_WT2  9248   // 24
#define F_SML  13824  // 1600
#define F_SW1  15424  // 384
#define F_CIN  15808  // 160
#define F_ESRC 15968  // 24 (int)
#define F_EDST 15992  // 24 (int)
#define F_SB1  16016  // 32
#define F_SB2  16048  // 64
#define F_SDB  16112  // 16
#define F_VM0  16128  // 64
#define SM_TOT 16192

// ================= K1: parallel precompute (12 blocks x 256) =================
__global__ __launch_bounds__(256) void k1_pre(
    const float* __restrict__ xf,   const float* __restrict__ xft,
    const float* __restrict__ ea,
    const float* __restrict__ c1w1, const float* __restrict__ c1b1,
    const float* __restrict__ c1w2, const float* __restrict__ c1b2,
    const float* __restrict__ g1lin,const float* __restrict__ g1le,
    const float* __restrict__ g1ae,
    const float* __restrict__ mw1,  const float* __restrict__ mb1,
    const float* __restrict__ mw2,  const float* __restrict__ mb2,
    const float* __restrict__ g2le, const float* __restrict__ g2ae,
    const float* __restrict__ l1w,  const float* __restrict__ l1b,
    const float* __restrict__ l2w,  const float* __restrict__ l2b,
    float* __restrict__ ws)
{
    const int b = blockIdx.x, tid = threadIdx.x;
    if (b < 4) {
        // ---------- HX chunk b: k in [b*128, b*128+klen), 510 = 3*128+126 ----------
        // SINGLE CHANGE vs R11: 8-wide load batching (8 g1lin loads in flight
        // per waitcnt instead of a rolled load->use chain).
        __shared__ float sx[1024];            // [8][128]
        const int k0 = b * 128;
        const int klen = (b == 3) ? 126 : 128;
        for (int idx = tid; idx < 1024; idx += 256) {
            int n = idx >> 7, kk = idx & 127;
            sx[n * 128 + kk] = (kk < klen) ? xf[n * 510 + k0 + kk] : 0.f;
        }
        __syncthreads();
        float acc[8];
        #pragma unroll
        for (int n = 0; n < 8; ++n) acc[n] = 0.f;
        for (int kb = 0; kb < 128; kb += 8) {
            float w[8];
            #pragma unroll
            for (int u = 0; u < 8; ++u)
                w[u] = g1lin[(k0 + kb + u) * 256 + tid];   // rows 510/511 hit *0 -> harmless
            #pragma unroll
            for (int u = 0; u < 8; ++u)
                #pragma unroll
                for (int n = 0; n < 8; ++n) acc[n] += sx[n * 128 + kb + u] * w[u];
        }
        #pragma unroll
        for (int n = 0; n < 8; ++n)
            ws[WS_HXPART + ((n * 256 + tid) << 2) + b] = acc[n];
    } else if (b < 6) {
        // ---------- se1 half-fold: q1h = g1le[k-half] @ a_e ; se1 part ----------
        __shared__ float seaC[1088];          // [17][64] (row 16 = mean)
        __shared__ float sae[256], q1h[256];
        const int kh = b - 4, k0 = kh * 64;
        for (int idx = tid; idx < 1024; idx += 256) {
            int e = idx >> 6, kk = idx & 63;
            seaC[e * 64 + kk] = ea[e * 128 + k0 + kk];
        }
        sae[tid] = g1ae[tid];
        __syncthreads();
        if (tid < 64) {
            float m = 0.f;
            for (int e = 0; e < 16; ++e) m += seaC[e * 64 + tid];
            seaC[1024 + tid] = m * (1.f / 16.f);
        }
        __syncthreads();
        {
            int kk = tid >> 2, hd = tid & 3;
            float acc = 0.f;
            for (int c = 0; c < 64; ++c)
                acc += g1le[(k0 + kk) * 256 + hd * 64 + c] * sae[hd * 64 + c];
            q1h[tid] = acc;
        }
        __syncthreads();
        if (tid < 68) {
            int e = tid >> 2, hd = tid & 3;
            int row = (tid < 64) ? e : 16;
            if (tid >= 64) hd = tid - 64;
            float acc = 0.f;
            for (int kk = 0; kk < 64; ++kk) acc += seaC[row * 64 + kk] * q1h[kk * 4 + hd];
            int dst = (tid < 64) ? tid : (64 + hd);
            ws[WS_SMALL + ((kh == 0) ? SM_SE1A : SM_SE1B) + dst] = acc;
        }
    } else if (b == 6) {
        // ---------- edge MLP -> ea_new ; even/odd means ; q2-fold ; se2 ----------
        __shared__ float sea[2048];
        __shared__ float tmp[1024];
        __shared__ float ean[17 * 64];
        __shared__ float sq2a[64], sq2[64];
        for (int idx = tid; idx < 2048; idx += 256) sea[idx] = ea[idx];
        if (tid < 64) sq2a[tid] = g2ae[tid];
        __syncthreads();
        for (int o = tid; o < 1024; o += 256) {
            int e = o >> 6, c = o & 63;
            float acc = mb1[c];
            for (int k = 0; k < 128; ++k) acc += sea[e * 128 + k] * mw1[k * 64 + c];
            tmp[o] = fmaxf(acc, 0.f);
        }
        __syncthreads();
        for (int o = tid; o < 1024; o += 256) {
            int e = o >> 6, c = o & 63;
            float acc = mb2[c];
            for (int k = 0; k < 64; ++k) acc += tmp[e * 64 + k] * mw2[k * 64 + c];
            ean[o] = acc;
        }
        __syncthreads();
        if (tid < 64) {
            float m = 0.f;
            for (int e = 0; e < 16; ++e) m += ean[e * 64 + tid];
            ean[1024 + tid] = m * (1.f / 16.f);
        } else if (tid < 128) {
            int c = tid - 64;
            float m = 0.f;
            for (int e = 0; e < 16; e += 2) m += ean[e * 64 + c];
            ws[WS_SMALL + SM_VME + c] = m * 0.125f;
        } else if (tid < 192) {
            int c = tid - 128;
            float m = 0.f;
            for (int e = 1; e < 16; e += 2) m += ean[e * 64 + c];
            ws[WS_SMALL + SM_VME + 64 + c] = m * 0.125f;
        }
        __syncthreads();
        if (tid < 64) {
            float acc = 0.f;
            for (int c = 0; c < 64; ++c) acc += g2le[tid * 64 + c] * sq2a[c];
            sq2[tid] = acc;
        }
        __syncthreads();
        if (tid < 16) {
            float acc = 0.f;
            for (int k = 0; k < 64; ++k) acc += ean[tid * 64 + k] * sq2[k];
            ws[WS_SMALL + SM_SE2 + tid] = acc;
        } else if (tid == 16) {
            float acc = 0.f;
            for (int k = 0; k < 64; ++k) acc += ean[1024 + k] * sq2[k];
            ws[WS_SMALL + SM_SE2 + 16] = acc;
        }
    } else if (b == 7) {
        // ---------- CNN_1 (verified) ----------
        __shared__ float t2[160], y1[160], y2[16];
        if (tid < 160) {
            int b_ = tid / 80, ch = (tid % 80) / 10, tt = tid % 10;
            int srow = ((ch & 1) == 0) ? 1 : 5;
            int n = 4 * b_ + (ch >> 1);
            t2[tid] = xft[srow * 80 + n * 10 + tt];
        }
        __syncthreads();
        if (tid < 160) {
            int b_ = tid / 80, co = (tid % 80) / 10, tt = tid % 10;
            float acc = c1b1[co];
            for (int ci = 0; ci < 8; ++ci)
                for (int k = 0; k < 3; ++k) {
                    int p = tt + k - 1;
                    if (p >= 0 && p < 10) acc += t2[b_ * 80 + ci * 10 + p] * c1w1[co * 24 + ci * 3 + k];
                }
            y1[tid] = fmaxf(acc, 0.f);
        }
        __syncthreads();
        if (tid < 16) {
            int b_ = tid >> 3, p = tid & 7;
            float acc = c1b2[0];
            for (int i = 0; i < 10; ++i)
                for (int k = 0; k < 3; ++k) {
                    int q = p + k - 1;
                    if (q >= 0 && q < 8) acc += y1[b_ * 80 + q * 10 + i] * c1w2[i * 3 + k];
                }
            y2[tid] = acc;
        }
        __syncthreads();
        if (tid < 16) ws[WS_SMALL + SM_XCNN + tid] = fmaxf(y2[tid], 0.f);
    } else {
        // ---------- fused tail linear: wf = c2l1w @ c2l2w (+ bf on b8) ----------
        __shared__ float sl2[2560];
        for (int idx = tid; idx < 2560; idx += 256) sl2[idx] = l2w[idx];
        __syncthreads();
        const int m0 = (b - 8) * 32;
        for (int o = tid; o < 320; o += 256) {
            int ml = o / 10, t = o % 10, m = m0 + ml;
            float acc = 0.f;
            for (int j = 0; j < 256; ++j) acc += l1w[m * 256 + j] * sl2[j * 10 + t];
            ws[WS_SMALL + SM_WF + m * 10 + t] = acc;
        }
        if (b == 8 && tid < 10) {
            float acc = l2b[tid];
            for (int j = 0; j < 256; ++j) acc += l1b[j] * sl2[j * 10 + tid];
            ws[WS_SMALL + SM_BF + tid] = acc;
        }
    }
}

// ======== K2: wave-parallel GAT chain + per-block tail (16 blocks x 512) =====
__global__ __launch_bounds__(512) void k2_main(
    const float* __restrict__ xft,
    const float* __restrict__ g1lin,
    const float* __restrict__ g1as, const float* __restrict__ g1ad,
    const float* __restrict__ g1b,
    const float* __restrict__ g2lin,
    const float* __restrict__ g2as, const float* __restrict__ g2ad,
    const float* __restrict__ g2b,
    const int* __restrict__ eidx,
    const float* __restrict__ d1w, const float* __restrict__ d1b,
    const float* __restrict__ d2w, const float* __restrict__ d2b,
    const float* __restrict__ d3w, const float* __restrict__ d3b,
    const float* __restrict__ c2w1, const float* __restrict__ c2b1,
    const float* __restrict__ c2w2, const float* __restrict__ c2b2,
    const float* __restrict__ ws, float* __restrict__ out)
{
    __shared__ float sm[SM_TOT];
    const int tid = threadIdx.x;
    const int r0 = blockIdx.x * 4;
    int* esrc = (int*)sm + F_ESRC;
    int* edst = (int*)sm + F_EDST;

    // ---- S0a: issue critical-path register loads FIRST (HXPART float4) ----
    const int jj = tid & 255, hf = tid >> 8;
    float4 rH[4];
    #pragma unroll
    for (int nl = 0; nl < 4; ++nl)
        rH[nl] = *(const float4*)&ws[WS_HXPART + (((hf * 4 + nl) * 256 + jj) << 2)];
    // sml mirror (float4, 400 threads)
    if (tid < 400)
        *(float4*)&sm[F_SML + tid * 4] = *(const float4*)&ws[WS_SMALL + tid * 4];
    // ---- S0b: small weights to LDS ----
    if (tid < 256) {
        sm[F_G1AS + tid] = g1as[tid];
        sm[F_G1AD + tid] = g1ad[tid];
        sm[F_G1B  + tid] = g1b[tid];
        sm[F_GL0  + tid] = g1lin[510 * 256 + tid];
        sm[F_GL1  + tid] = g1lin[511 * 256 + tid];
    } else {
        int j = tid - 256;
        if (j < 64)       { sm[F_G2AS + j] = g2as[j]; sm[F_G2AD + j] = g2ad[j]; sm[F_G2B + j] = g2b[j]; }
        else if (j < 88)  { int i = j - 64;  esrc[i] = (i < 16) ? eidx[i] : i - 16;
                                             edst[i] = (i < 16) ? eidx[16 + i] : i - 16; }
        else if (j < 128) { int i = j - 88;  int rl = i / 10, t = i % 10;
                            sm[F_CIN + rl * 40 + 10 + t] = xft[(r0 + rl) * 10 + t]; }
        else if (j < 160) sm[F_SB1 + j - 128] = c2b1[j - 128];
        else if (j < 224) sm[F_SB2 + j - 160] = c2b2[j - 160];
        else if (j < 236) { int i = j - 224, tau = i / 4, rl = i % 4;
                            const float* db = (tau == 0) ? d1b : (tau == 1) ? d2b : d3b;
                            sm[F_SDB + i] = db[r0 + rl]; }
    }
    for (int idx = tid; idx < 384; idx += 512) sm[F_SW1 + idx] = c2w1[idx];
    // ---- S0c: tail weights to registers (consumed only at the tail) ----
    float rA[15], rW[12];
    {
        int ii = tid / 40, rem = tid - (tid / 40) * 40;
        #pragma unroll
        for (int i = 0; i < 15; ++i) {
            const float* dw = (ii < 64) ? d1w : (ii < 128) ? d2w : d3w;
            rA[i] = dw[(ii & 63) * 640 + r0 * 10 + rem];
            ii += 12; rem += 32; if (rem >= 40) { rem -= 40; ++ii; }
        }
    }
    #pragma unroll
    for (int i = 0; i < 12; ++i) rW[i] = c2w2[tid + 512 * i];
    // ---- S0d: prefetch-touch g2lin (warm local L2 for the h2 phase) ----
    {
        float p0 = g2lin[tid * 32], p1 = g2lin[tid * 32 + 16];
        asm volatile("" :: "v"(p0), "v"(p1));
    }
    __syncthreads();

    // ---- S1: h = register partial sums + CNN columns ----
    #pragma unroll
    for (int nl = 0; nl < 4; ++nl) {
        int n = hf * 4 + nl;
        float acc = ((rH[nl].x + rH[nl].y) + rH[nl].z) + rH[nl].w;
        acc += sm[F_SML + SM_XCNN + n * 2] * sm[F_GL0 + jj]
             + sm[F_SML + SM_XCNN + n * 2 + 1] * sm[F_GL1 + jj];
        sm[F_H + n * 256 + jj] = acc;
    }
    __syncthreads();
    // ---- sc1: ss1/sd1 via 16-lane groups ----
    {
        int p = tid >> 4, g = tid & 15, n = p >> 2, hd = p & 3;
        float aS = 0.f, aD = 0.f;
        #pragma unroll
        for (int cc = 0; cc < 4; ++cc) {
            int c = (((cc + p) & 3) << 4) + g;
            float hv = sm[F_H + n * 256 + hd * 64 + c];
            aS += hv * sm[F_G1AS + hd * 64 + c];
            aD += hv * sm[F_G1AD + hd * 64 + c];
        }
        #pragma unroll
        for (int m = 8; m >= 1; m >>= 1) { aS += __shfl_xor(aS, m); aD += __shfl_xor(aD, m); }
        if (g == 0) { sm[F_SS1 + p] = aS; sm[F_SD1 + p] = aD; }
    }
    __syncthreads();
    // ---- stat1: masked max/sum, al inline ----
    {
        int p = tid >> 4, g = tid & 15, n = p >> 2, hd = p & 3;
        #define AL1(e) ({ int _e = (e); \
            float _se = (_e < 16) ? (sm[F_SML+SM_SE1A+_e*4+hd] + sm[F_SML+SM_SE1B+_e*4+hd]) \
                                  : (sm[F_SML+SM_SE1A+64+hd]   + sm[F_SML+SM_SE1B+64+hd]); \
            float _s = sm[F_SS1 + esrc[_e]*4+hd] + sm[F_SD1 + edst[_e]*4+hd] + _se; \
            (_s > 0.f) ? _s : 0.2f * _s; })
        float v1 = (edst[g] == n) ? AL1(g) : -1e30f;
        float v2 = (g < 8 && edst[g + 16] == n) ? AL1(g + 16) : -1e30f;
        float mx = fmaxf(v1, v2);
        #pragma unroll
        for (int m = 8; m >= 1; m >>= 1) mx = fmaxf(mx, __shfl_xor(mx, m));
        float ex = expf(v1 - mx) + ((g < 8) ? expf(v2 - mx) : 0.f);
        #pragma unroll
        for (int m = 8; m >= 1; m >>= 1) ex += __shfl_xor(ex, m);
        if (g == 0) { sm[F_MX1 + p] = mx; sm[F_DN1 + p] = ex; }
    }
    __syncthreads();
    if (tid < 96) {   // wt1 (al inline)
        int e = tid >> 2, hd = tid & 3, d = edst[e];
        float al = AL1(e);
        sm[F_WT1 + tid] = expf(al - sm[F_MX1 + d * 4 + hd]) / (sm[F_DN1 + d * 4 + hd] + 1e-16f);
        #undef AL1
    }
    __syncthreads();
    if (tid < 256) {  // A1[s][n][hd], branchless
        int s = tid >> 5, n = (tid >> 2) & 7, hd = tid & 3;
        float acc = 0.f;
        #pragma unroll
        for (int e = 0; e < 24; ++e)
            acc += (edst[e] == n && esrc[e] == s) ? sm[F_WT1 + e * 4 + hd] : 0.f;
        sm[F_A1 + tid] = acc;
    }
    __syncthreads();
    // ---- x1 = relu(A1 @ h + b) ----
    {
        const int hd = jj >> 6;
        #pragma unroll
        for (int nl = 0; nl < 4; ++nl) {
            int n = hf * 4 + nl;
            float acc = 0.f;
            #pragma unroll
            for (int s = 0; s < 8; ++s)
                acc += sm[F_A1 + s * 32 + n * 4 + hd] * sm[F_H + s * 256 + jj];
            sm[F_X1 + n * 256 + jj] = fmaxf(acc + sm[F_G1B + jj], 0.f);
        }
    }
    __syncthreads();
    // ---- h2 partials (g2lin L2-warm) + early rW dump (free LDS region) ----
    {
        const int kc = tid >> 7, sub = (tid >> 6) & 1, c = tid & 63;
        float p0 = 0.f, p1 = 0.f, p2 = 0.f, p3 = 0.f;
        for (int kk = 0; kk < 64; ++kk) {
            int k = kc * 64 + kk;
            float g = g2lin[k * 64 + c];
            p0 += sm[F_X1 + (sub * 4 + 0) * 256 + k] * g;
            p1 += sm[F_X1 + (sub * 4 + 1) * 256 + k] * g;
            p2 += sm[F_X1 + (sub * 4 + 2) * 256 + k] * g;
            p3 += sm[F_X1 + (sub * 4 + 3) * 256 + k] * g;
        }
        sm[F_H2P + kc * 512 + (sub * 4 + 0) * 64 + c] = p0;
        sm[F_H2P + kc * 512 + (sub * 4 + 1) * 64 + c] = p1;
        sm[F_H2P + kc * 512 + (sub * 4 + 2) * 64 + c] = p2;
        sm[F_H2P + kc * 512 + (sub * 4 + 3) * 64 + c] = p3;
        #pragma unroll
        for (int i = 4; i < 12; ++i) sm[F_SW2 + tid + 512 * i] = rW[i];
    }
    __syncthreads();
    // ---- h2 reduce + sc2 fused ----
    {
        int n = tid >> 6, c = tid & 63;
        float hv = sm[F_H2P + n * 64 + c] + sm[F_H2P + 512 + n * 64 + c]
                 + sm[F_H2P + 1024 + n * 64 + c] + sm[F_H2P + 1536 + n * 64 + c];
        sm[F_H2 + n * 64 + c] = hv;
        float aS = hv * sm[F_G2AS + c], aD = hv * sm[F_G2AD + c];
        #pragma unroll
        for (int m = 32; m >= 1; m >>= 1) { aS += __shfl_xor(aS, m); aD += __shfl_xor(aD, m); }
        if (c == 0) { sm[F_SS2 + n] = aS; sm[F_SD2 + n] = aD; }
    }
    __syncthreads();
    // ---- stat2 (al2 inline) ----
    {
        #define AL2(e) ({ int _e = (e); \
            float _s = sm[F_SS2 + esrc[_e]] + sm[F_SD2 + edst[_e]] \
                     + sm[F_SML + SM_SE2 + ((_e < 16) ? _e : 16)]; \
            (_s > 0.f) ? _s : 0.2f * _s; })
        if (tid < 256) {
            int n = tid >> 5, g = tid & 31;
            float v = (g < 24 && edst[g] == n) ? AL2(g) : -1e30f;
            float mx = v;
            #pragma unroll
            for (int m = 16; m >= 1; m >>= 1) mx = fmaxf(mx, __shfl_xor(mx, m));
            float ex = expf(v - mx);
            #pragma unroll
            for (int m = 16; m >= 1; m >>= 1) ex += __shfl_xor(ex, m);
            if (g == 0) { sm[F_MX2 + n] = mx; sm[F_DN2 + n] = ex; }
        }
    }
    __syncthreads();
    if (tid < 24) {   // wt2 (al2 inline)
        int d = edst[tid];
        float al = AL2(tid);
        sm[F_WT2 + tid] = expf(al - sm[F_MX2 + d]) / (sm[F_DN2 + d] + 1e-16f);
        #undef AL2
    }
    __syncthreads();
    if (tid < 64) {   // A2
        int n = tid >> 3, s = tid & 7;
        float acc = 0.f;
        #pragma unroll
        for (int e = 0; e < 24; ++e)
            acc += (edst[e] == n && esrc[e] == s) ? sm[F_WT2 + e] : 0.f;
        sm[F_A2 + tid] = acc;
    }
    __syncthreads();
    {   // x2 = relu(A2 @ h2 + b2)
        int n = tid >> 6, c = tid & 63;
        float acc = 0.f;
        #pragma unroll
        for (int s = 0; s < 8; ++s) acc += sm[F_A2 + n * 8 + s] * sm[F_H2 + s * 64 + c];
        sm[F_X2 + n * 64 + c] = fmaxf(acc + sm[F_G2B + c], 0.f);
    }
    __syncthreads();
    if (tid < 64) {   // vm0 = mean_n(x2)
        float m = 0.f;
        #pragma unroll
        for (int n = 0; n < 8; ++n) m += sm[F_X2 + n * 64 + tid];
        sm[F_VM0 + tid] = m * 0.125f;
    }
    __syncthreads();   // ---- front dead ----

    // ---- dump remaining register-staged tail weights ----
    #pragma unroll
    for (int i = 0; i < 15; ++i) sm[tid + 512 * i] = rA[i];
    #pragma unroll
    for (int i = 0; i < 4; ++i) sm[F_SW2 + tid + 512 * i] = rW[i];
    __syncthreads();
    // ---- deconv: 120 outputs x 4-lane split ----
    if (tid < 480) {
        int o = tid >> 2, q = tid & 3;
        int t = o % 10, tau = (o / 10) % 3, rl = o / 30;
        float acc = 0.f;
        for (int i = q * 16; i < q * 16 + 16; ++i) {
            float vm = (tau == 0) ? sm[F_VM0 + i]
                     : (tau == 1) ? sm[F_SML + SM_VME + i]
                                  : sm[F_SML + SM_VME + 64 + i];
            acc += vm * sm[(tau * 64 + i) * 40 + rl * 10 + t];
        }
        acc += __shfl_xor(acc, 2); acc += __shfl_xor(acc, 1);
        if (q == 0) {
            int ch = (tau == 0) ? 0 : (tau + 1);
            sm[F_CIN + rl * 40 + ch * 10 + t] = acc + sm[F_SDB + tau * 4 + rl];
        }
    }
    __syncthreads();
    for (int o = tid; o < 1024; o += 512) {   // conv1 -> u @ sm[4096..5120)
        int rl = o >> 8, co = (o >> 3) & 31, p = o & 7;
        float acc = sm[F_SB1 + co];
        #pragma unroll
        for (int ci = 0; ci < 4; ++ci)
            #pragma unroll
            for (int k = 0; k < 3; ++k)
                acc += sm[F_CIN + rl * 40 + ci * 10 + p + k] * sm[F_SW1 + co * 12 + ci * 3 + k];
        sm[4096 + o] = acc;
    }
    __syncthreads();
    {   // conv2 + inline maxpool -> f @ sm[1024..1536)
        int rl = tid >> 7, m = tid & 127, co2 = m >> 1, p = m & 1;
        float acc = sm[F_SB2 + co2];
        for (int ci = 0; ci < 32; ++ci)
            #pragma unroll
            for (int k = 0; k < 3; ++k) {
                int u0 = 4096 + rl * 256 + ci * 8 + 2 * (p + k);
                acc += fmaxf(sm[u0], sm[u0 + 1]) * sm[F_SW2 + co2 * 96 + ci * 3 + k];
            }
        sm[1024 + rl * 128 + m] = acc;
    }
    __syncthreads();
    if (tid < 320) {  // fused (l1->l2) + relu, 8-lane split
        int o = tid >> 3, l = tid & 7;
        int rl = o / 10, t = o % 10;
        float acc = 0.f;
        for (int m = l * 16; m < l * 16 + 16; ++m)
            acc += sm[1024 + rl * 128 + m] * sm[F_SML + SM_WF + m * 10 + t];
        acc += __shfl_xor(acc, 4); acc += __shfl_xor(acc, 2); acc += __shfl_xor(acc, 1);
        if (l == 0)
            out[(r0 + rl) * 10 + t] = fmaxf(acc + sm[F_SML + SM_BF + t], 0.f);
    }
}

extern "C" void kernel_launch(void* const* d_in, const int* in_sizes, int n_in,
                              void* d_out, int out_size, void* d_ws, size_t ws_size,
                              hipStream_t stream)
{
    const float* xf    = (const float*)d_in[0];
    const float* xft   = (const float*)d_in[1];
    const float* ea    = (const float*)d_in[2];
    const float* c1w1  = (const float*)d_in[3];
    const float* c1b1  = (const float*)d_in[4];
    const float* c1w2  = (const float*)d_in[5];
    const float* c1b2  = (const float*)d_in[6];
    const float* g1lin = (const float*)d_in[7];
    const float* g1as  = (const float*)d_in[8];
    const float* g1ad  = (const float*)d_in[9];
    const float* g1le  = (const float*)d_in[10];
    const float* g1ae  = (const float*)d_in[11];
    const float* g1b   = (const float*)d_in[12];
    const float* g2lin = (const float*)d_in[13];
    const float* g2as  = (const float*)d_in[14];
    const float* g2ad  = (const float*)d_in[15];
    const float* g2le  = (const float*)d_in[16];
    const float* g2ae  = (const float*)d_in[17];
    const float* g2b   = (const float*)d_in[18];
    const float* mw1   = (const float*)d_in[19];
    const float* mb1   = (const float*)d_in[20];
    const float* mw2   = (const float*)d_in[21];
    const float* mb2   = (const float*)d_in[22];
    const float* d1w   = (const float*)d_in[23];
    const float* d1b   = (const float*)d_in[24];
    const float* d2w   = (const float*)d_in[25];
    const float* d2b   = (const float*)d_in[26];
    const float* d3w   = (const float*)d_in[27];
    const float* d3b   = (const float*)d_in[28];
    const float* c2w1  = (const float*)d_in[29];
    const float* c2b1  = (const float*)d_in[30];
    const float* c2w2  = (const float*)d_in[31];
    const float* c2b2  = (const float*)d_in[32];
    const float* l1w   = (const float*)d_in[33];
    const float* l1b   = (const float*)d_in[34];
    const float* l2w   = (const float*)d_in[35];
    const float* l2b   = (const float*)d_in[36];
    const int*   eidx  = (const int*)d_in[37];
    float* ws  = (float*)d_ws;
    float* out = (float*)d_out;

    hipLaunchKernelGGL(k1_pre, dim3(12), dim3(256), 0, stream,
        xf, xft, ea, c1w1, c1b1, c1w2, c1b2,
        g1lin, g1le, g1ae, mw1, mb1, mw2, mb2,
        g2le, g2ae, l1w, l1b, l2w, l2b, ws);
    hipLaunchKernelGGL(k2_main, dim3(16), dim3(512), 0, stream,
        xft, g1lin, g1as, g1ad, g1b,
        g2lin, g2as, g2ad, g2b, eidx,
        d1w, d1b, d2w, d2b, d3w, d3b,
        c2w1, c2b1, c2w2, c2b2, ws, out);
}

// Round 13
// 33.115 us; speedup vs baseline: 1.0820x; 1.0820x over previous
//
#include <hip/hip_runtime.h>
#include <math.h>

// ---------------- workspace layout (float offsets) ----------------
#define WS_HXPART 0          // [(n*256+j)*4 + cb] : 4 k-chunks of x@g1_lin[:510]
#define WS_SMALL  8192       // contiguous small block, mirrored to k2 LDS
#define SM_XCNN 0            // 16
#define SM_SE1A 16           // 68 (e*4+hd; self-loop at 64+hd)
#define SM_SE1B 84           // 68
#define SM_SE2  152          // 17
#define SM_WF   172          // 1280
#define SM_BF   1452         // 10
#define SM_VME  1462         // 128: even mean 0-64, odd mean 64-128
#define SM_SIZE 1600

// ---------------- k2 LDS map (floats) ----------------
#define F_H    0      // 2048 (tail: rA dump region 0..7680; then u@4096, f@1024)
#define F_X1   2048   // 2048
#define F_H2P  4096   // 2048
#define F_GL0  6144   // 256
#define F_GL1  6400   // 256
#define F_G1AS 6656   // 256
#define F_G1AD 6912   // 256
#define F_G1B  7168   // 256
#define F_SS1  7424   // 32
#define F_SD1  7456   // 32
#define F_MX1  7488   // 32
#define F_DN1  7520   // 32
#define F_WT1  7552   // 96
#define F_SW2  7680   // 6144 (tail); front GAT2 regions reuse 7680..9728
#define F_A1   7680   // 256
#define F_H2   7936   // 512
#define F_X2   8448   // 512
#define F_G2AS 8960   // 64
#define F_G2AD 9024   // 64
#define F_G2B  9088   // 64
#define F_SS2  9152   // 8
#define F_SD2  9160   // 8
#define F_MX2  9168   // 8
#define F_DN2  9176   // 8
#define F_A2   9184   // 64
#define F_WT2  9248   // 24
#define F_SML  13824  // 1600
#define F_SW1  15424  // 384
#define F_CIN  15808  // 160
#define F_ESRC 15968  // 24 (int)
#define F_EDST 15992  // 24 (int)
#define F_SB1  16016  // 32
#define F_SB2  16048  // 64
#define F_SDB  16112  // 16
#define F_VM0  16128  // 64
#define SM_TOT 16192

// ================= K1: parallel precompute (12 blocks x 256) =================
__global__ __launch_bounds__(256) void k1_pre(
    const float* __restrict__ xf,   const float* __restrict__ xft,
    const float* __restrict__ ea,
    const float* __restrict__ c1w1, const float* __restrict__ c1b1,
    const float* __restrict__ c1w2, const float* __restrict__ c1b2,
    const float* __restrict__ g1lin,const float* __restrict__ g1le,
    const float* __restrict__ g1ae,
    const float* __restrict__ mw1,  const float* __restrict__ mb1,
    const float* __restrict__ mw2,  const float* __restrict__ mb2,
    const float* __restrict__ g2le, const float* __restrict__ g2ae,
    const float* __restrict__ l1w,  const float* __restrict__ l1b,
    const float* __restrict__ l2w,  const float* __restrict__ l2b,
    float* __restrict__ ws)
{
    const int b = blockIdx.x, tid = threadIdx.x;
    if (b < 4) {
        // ---------- HX chunk b: k in [b*128, b*128+klen), 510 = 3*128+126 ----------
        __shared__ float sx[1024];            // [8][128]
        const int k0 = b * 128;
        const int klen = (b == 3) ? 126 : 128;
        for (int idx = tid; idx < 1024; idx += 256) {
            int n = idx >> 7, kk = idx & 127;
            sx[n * 128 + kk] = (kk < klen) ? xf[n * 510 + k0 + kk] : 0.f;
        }
        __syncthreads();
        float acc[8];
        #pragma unroll
        for (int n = 0; n < 8; ++n) acc[n] = 0.f;
        for (int kk = 0; kk < 128; ++kk) {
            float w = g1lin[(k0 + kk) * 256 + tid];   // rows 510/511 hit *0 -> harmless
            #pragma unroll
            for (int n = 0; n < 8; ++n) acc[n] += sx[n * 128 + kk] * w;
        }
        #pragma unroll
        for (int n = 0; n < 8; ++n)
            ws[WS_HXPART + ((n * 256 + tid) << 2) + b] = acc[n];
    } else if (b < 6) {
        // ---------- se1 half-fold: q1h = g1le[k-half] @ a_e ; se1 part ----------
        __shared__ float seaC[1088];          // [17][64] (row 16 = mean)
        __shared__ float sae[256], q1h[256];
        const int kh = b - 4, k0 = kh * 64;
        for (int idx = tid; idx < 1024; idx += 256) {
            int e = idx >> 6, kk = idx & 63;
            seaC[e * 64 + kk] = ea[e * 128 + k0 + kk];
        }
        sae[tid] = g1ae[tid];
        __syncthreads();
        if (tid < 64) {
            float m = 0.f;
            for (int e = 0; e < 16; ++e) m += seaC[e * 64 + tid];
            seaC[1024 + tid] = m * (1.f / 16.f);
        }
        __syncthreads();
        {
            int kk = tid >> 2, hd = tid & 3;
            float acc = 0.f;
            for (int c = 0; c < 64; ++c)
                acc += g1le[(k0 + kk) * 256 + hd * 64 + c] * sae[hd * 64 + c];
            q1h[tid] = acc;
        }
        __syncthreads();
        if (tid < 68) {
            int e = tid >> 2, hd = tid & 3;
            int row = (tid < 64) ? e : 16;
            if (tid >= 64) hd = tid - 64;
            float acc = 0.f;
            for (int kk = 0; kk < 64; ++kk) acc += seaC[row * 64 + kk] * q1h[kk * 4 + hd];
            int dst = (tid < 64) ? tid : (64 + hd);
            ws[WS_SMALL + ((kh == 0) ? SM_SE1A : SM_SE1B) + dst] = acc;
        }
    } else if (b == 6) {
        // ---------- edge MLP -> ea_new ; even/odd means ; q2-fold ; se2 ----------
        __shared__ float sea[2048];
        __shared__ float tmp[1024];
        __shared__ float ean[17 * 64];
        __shared__ float sq2a[64], sq2[64];
        for (int idx = tid; idx < 2048; idx += 256) sea[idx] = ea[idx];
        if (tid < 64) sq2a[tid] = g2ae[tid];
        __syncthreads();
        for (int o = tid; o < 1024; o += 256) {
            int e = o >> 6, c = o & 63;
            float acc = mb1[c];
            for (int k = 0; k < 128; ++k) acc += sea[e * 128 + k] * mw1[k * 64 + c];
            tmp[o] = fmaxf(acc, 0.f);
        }
        __syncthreads();
        for (int o = tid; o < 1024; o += 256) {
            int e = o >> 6, c = o & 63;
            float acc = mb2[c];
            for (int k = 0; k < 64; ++k) acc += tmp[e * 64 + k] * mw2[k * 64 + c];
            ean[o] = acc;
        }
        __syncthreads();
        if (tid < 64) {
            float m = 0.f;
            for (int e = 0; e < 16; ++e) m += ean[e * 64 + tid];
            ean[1024 + tid] = m * (1.f / 16.f);
        } else if (tid < 128) {
            int c = tid - 64;
            float m = 0.f;
            for (int e = 0; e < 16; e += 2) m += ean[e * 64 + c];
            ws[WS_SMALL + SM_VME + c] = m * 0.125f;
        } else if (tid < 192) {
            int c = tid - 128;
            float m = 0.f;
            for (int e = 1; e < 16; e += 2) m += ean[e * 64 + c];
            ws[WS_SMALL + SM_VME + 64 + c] = m * 0.125f;
        }
        __syncthreads();
        if (tid < 64) {
            float acc = 0.f;
            for (int c = 0; c < 64; ++c) acc += g2le[tid * 64 + c] * sq2a[c];
            sq2[tid] = acc;
        }
        __syncthreads();
        if (tid < 16) {
            float acc = 0.f;
            for (int k = 0; k < 64; ++k) acc += ean[tid * 64 + k] * sq2[k];
            ws[WS_SMALL + SM_SE2 + tid] = acc;
        } else if (tid == 16) {
            float acc = 0.f;
            for (int k = 0; k < 64; ++k) acc += ean[1024 + k] * sq2[k];
            ws[WS_SMALL + SM_SE2 + 16] = acc;
        }
    } else if (b == 7) {
        // ---------- CNN_1 (verified) ----------
        __shared__ float t2[160], y1[160], y2[16];
        if (tid < 160) {
            int b_ = tid / 80, ch = (tid % 80) / 10, tt = tid % 10;
            int srow = ((ch & 1) == 0) ? 1 : 5;
            int n = 4 * b_ + (ch >> 1);
            t2[tid] = xft[srow * 80 + n * 10 + tt];
        }
        __syncthreads();
        if (tid < 160) {
            int b_ = tid / 80, co = (tid % 80) / 10, tt = tid % 10;
            float acc = c1b1[co];
            for (int ci = 0; ci < 8; ++ci)
                for (int k = 0; k < 3; ++k) {
                    int p = tt + k - 1;
                    if (p >= 0 && p < 10) acc += t2[b_ * 80 + ci * 10 + p] * c1w1[co * 24 + ci * 3 + k];
                }
            y1[tid] = fmaxf(acc, 0.f);
        }
        __syncthreads();
        if (tid < 16) {
            int b_ = tid >> 3, p = tid & 7;
            float acc = c1b2[0];
            for (int i = 0; i < 10; ++i)
                for (int k = 0; k < 3; ++k) {
                    int q = p + k - 1;
                    if (q >= 0 && q < 8) acc += y1[b_ * 80 + q * 10 + i] * c1w2[i * 3 + k];
                }
            y2[tid] = acc;
        }
        __syncthreads();
        if (tid < 16) ws[WS_SMALL + SM_XCNN + tid] = fmaxf(y2[tid], 0.f);
    } else {
        // ---------- fused tail linear: wf = c2l1w @ c2l2w (+ bf on b8) ----------
        __shared__ float sl2[2560];
        for (int idx = tid; idx < 2560; idx += 256) sl2[idx] = l2w[idx];
        __syncthreads();
        const int m0 = (b - 8) * 32;
        for (int o = tid; o < 320; o += 256) {
            int ml = o / 10, t = o % 10, m = m0 + ml;
            float acc = 0.f;
            for (int j = 0; j < 256; ++j) acc += l1w[m * 256 + j] * sl2[j * 10 + t];
            ws[WS_SMALL + SM_WF + m * 10 + t] = acc;
        }
        if (b == 8 && tid < 10) {
            float acc = l2b[tid];
            for (int j = 0; j < 256; ++j) acc += l1b[j] * sl2[j * 10 + tid];
            ws[WS_SMALL + SM_BF + tid] = acc;
        }
    }
}

// ======== K2: wave-parallel GAT chain + per-block tail (16 blocks x 512) =====
__global__ __launch_bounds__(512) void k2_main(
    const float* __restrict__ xft,
    const float* __restrict__ g1lin,
    const float* __restrict__ g1as, const float* __restrict__ g1ad,
    const float* __restrict__ g1b,
    const float* __restrict__ g2lin,
    const float* __restrict__ g2as, const float* __restrict__ g2ad,
    const float* __restrict__ g2b,
    const int* __restrict__ eidx,
    const float* __restrict__ d1w, const float* __restrict__ d1b,
    const float* __restrict__ d2w, const float* __restrict__ d2b,
    const float* __restrict__ d3w, const float* __restrict__ d3b,
    const float* __restrict__ c2w1, const float* __restrict__ c2b1,
    const float* __restrict__ c2w2, const float* __restrict__ c2b2,
    const float* __restrict__ ws, float* __restrict__ out)
{
    __shared__ float sm[SM_TOT];
    const int tid = threadIdx.x;
    const int r0 = blockIdx.x * 4;
    int* esrc = (int*)sm + F_ESRC;
    int* edst = (int*)sm + F_EDST;

    // ---- S0a: issue critical-path register loads FIRST (HXPART float4) ----
    const int jj = tid & 255, hf = tid >> 8;
    float4 rH[4];
    #pragma unroll
    for (int nl = 0; nl < 4; ++nl)
        rH[nl] = *(const float4*)&ws[WS_HXPART + (((hf * 4 + nl) * 256 + jj) << 2)];
    // sml mirror (float4, 400 threads)
    if (tid < 400)
        *(float4*)&sm[F_SML + tid * 4] = *(const float4*)&ws[WS_SMALL + tid * 4];
    // ---- S0b: small weights to LDS ----
    if (tid < 256) {
        sm[F_G1AS + tid] = g1as[tid];
        sm[F_G1AD + tid] = g1ad[tid];
        sm[F_G1B  + tid] = g1b[tid];
        sm[F_GL0  + tid] = g1lin[510 * 256 + tid];
        sm[F_GL1  + tid] = g1lin[511 * 256 + tid];
    } else {
        int j = tid - 256;
        if (j < 64)       { sm[F_G2AS + j] = g2as[j]; sm[F_G2AD + j] = g2ad[j]; sm[F_G2B + j] = g2b[j]; }
        else if (j < 88)  { int i = j - 64;  esrc[i] = (i < 16) ? eidx[i] : i - 16;
                                             edst[i] = (i < 16) ? eidx[16 + i] : i - 16; }
        else if (j < 128) { int i = j - 88;  int rl = i / 10, t = i % 10;
                            sm[F_CIN + rl * 40 + 10 + t] = xft[(r0 + rl) * 10 + t]; }
        else if (j < 160) sm[F_SB1 + j - 128] = c2b1[j - 128];
        else if (j < 224) sm[F_SB2 + j - 160] = c2b2[j - 160];
        else if (j < 236) { int i = j - 224, tau = i / 4, rl = i % 4;
                            const float* db = (tau == 0) ? d1b : (tau == 1) ? d2b : d3b;
                            sm[F_SDB + i] = db[r0 + rl]; }
    }
    for (int idx = tid; idx < 384; idx += 512) sm[F_SW1 + idx] = c2w1[idx];
    // ---- S0c: tail weights to registers (consumed only at the tail) ----
    float rA[15], rW[12];
    {
        int ii = tid / 40, rem = tid - (tid / 40) * 40;
        #pragma unroll
        for (int i = 0; i < 15; ++i) {
            const float* dw = (ii < 64) ? d1w : (ii < 128) ? d2w : d3w;
            rA[i] = dw[(ii & 63) * 640 + r0 * 10 + rem];
            ii += 12; rem += 32; if (rem >= 40) { rem -= 40; ++ii; }
        }
    }
    #pragma unroll
    for (int i = 0; i < 12; ++i) rW[i] = c2w2[tid + 512 * i];
    // ---- S0d: prefetch-touch g2lin (warm local L2 for the h2 phase) ----
    {
        float p0 = g2lin[tid * 32], p1 = g2lin[tid * 32 + 16];
        asm volatile("" :: "v"(p0), "v"(p1));
    }
    __syncthreads();

    // ---- S1: h = register partial sums + CNN columns ----
    #pragma unroll
    for (int nl = 0; nl < 4; ++nl) {
        int n = hf * 4 + nl;
        float acc = ((rH[nl].x + rH[nl].y) + rH[nl].z) + rH[nl].w;
        acc += sm[F_SML + SM_XCNN + n * 2] * sm[F_GL0 + jj]
             + sm[F_SML + SM_XCNN + n * 2 + 1] * sm[F_GL1 + jj];
        sm[F_H + n * 256 + jj] = acc;
    }
    __syncthreads();
    // ---- sc1: ss1/sd1 via 16-lane groups ----
    {
        int p = tid >> 4, g = tid & 15, n = p >> 2, hd = p & 3;
        float aS = 0.f, aD = 0.f;
        #pragma unroll
        for (int cc = 0; cc < 4; ++cc) {
            int c = (((cc + p) & 3) << 4) + g;
            float hv = sm[F_H + n * 256 + hd * 64 + c];
            aS += hv * sm[F_G1AS + hd * 64 + c];
            aD += hv * sm[F_G1AD + hd * 64 + c];
        }
        #pragma unroll
        for (int m = 8; m >= 1; m >>= 1) { aS += __shfl_xor(aS, m); aD += __shfl_xor(aD, m); }
        if (g == 0) { sm[F_SS1 + p] = aS; sm[F_SD1 + p] = aD; }
    }
    __syncthreads();
    // ---- stat1: masked max/sum, al inline ----
    {
        int p = tid >> 4, g = tid & 15, n = p >> 2, hd = p & 3;
        #define AL1(e) ({ int _e = (e); \
            float _se = (_e < 16) ? (sm[F_SML+SM_SE1A+_e*4+hd] + sm[F_SML+SM_SE1B+_e*4+hd]) \
                                  : (sm[F_SML+SM_SE1A+64+hd]   + sm[F_SML+SM_SE1B+64+hd]); \
            float _s = sm[F_SS1 + esrc[_e]*4+hd] + sm[F_SD1 + edst[_e]*4+hd] + _se; \
            (_s > 0.f) ? _s : 0.2f * _s; })
        float v1 = (edst[g] == n) ? AL1(g) : -1e30f;
        float v2 = (g < 8 && edst[g + 16] == n) ? AL1(g + 16) : -1e30f;
        float mx = fmaxf(v1, v2);
        #pragma unroll
        for (int m = 8; m >= 1; m >>= 1) mx = fmaxf(mx, __shfl_xor(mx, m));
        float ex = expf(v1 - mx) + ((g < 8) ? expf(v2 - mx) : 0.f);
        #pragma unroll
        for (int m = 8; m >= 1; m >>= 1) ex += __shfl_xor(ex, m);
        if (g == 0) { sm[F_MX1 + p] = mx; sm[F_DN1 + p] = ex; }
    }
    __syncthreads();
    if (tid < 96) {   // wt1 (al inline)
        int e = tid >> 2, hd = tid & 3, d = edst[e];
        float al = AL1(e);
        sm[F_WT1 + tid] = expf(al - sm[F_MX1 + d * 4 + hd]) / (sm[F_DN1 + d * 4 + hd] + 1e-16f);
        #undef AL1
    }
    __syncthreads();
    if (tid < 256) {  // A1[s][n][hd], branchless
        int s = tid >> 5, n = (tid >> 2) & 7, hd = tid & 3;
        float acc = 0.f;
        #pragma unroll
        for (int e = 0; e < 24; ++e)
            acc += (edst[e] == n && esrc[e] == s) ? sm[F_WT1 + e * 4 + hd] : 0.f;
        sm[F_A1 + tid] = acc;
    }
    __syncthreads();
    // ---- x1 = relu(A1 @ h + b) ----
    {
        const int hd = jj >> 6;
        #pragma unroll
        for (int nl = 0; nl < 4; ++nl) {
            int n = hf * 4 + nl;
            float acc = 0.f;
            #pragma unroll
            for (int s = 0; s < 8; ++s)
                acc += sm[F_A1 + s * 32 + n * 4 + hd] * sm[F_H + s * 256 + jj];
            sm[F_X1 + n * 256 + jj] = fmaxf(acc + sm[F_G1B + jj], 0.f);
        }
    }
    __syncthreads();
    // ---- h2 partials (g2lin L2-warm) + early rW dump (free LDS region) ----
    {
        const int kc = tid >> 7, sub = (tid >> 6) & 1, c = tid & 63;
        float p0 = 0.f, p1 = 0.f, p2 = 0.f, p3 = 0.f;
        for (int kk = 0; kk < 64; ++kk) {
            int k = kc * 64 + kk;
            float g = g2lin[k * 64 + c];
            p0 += sm[F_X1 + (sub * 4 + 0) * 256 + k] * g;
            p1 += sm[F_X1 + (sub * 4 + 1) * 256 + k] * g;
            p2 += sm[F_X1 + (sub * 4 + 2) * 256 + k] * g;
            p3 += sm[F_X1 + (sub * 4 + 3) * 256 + k] * g;
        }
        sm[F_H2P + kc * 512 + (sub * 4 + 0) * 64 + c] = p0;
        sm[F_H2P + kc * 512 + (sub * 4 + 1) * 64 + c] = p1;
        sm[F_H2P + kc * 512 + (sub * 4 + 2) * 64 + c] = p2;
        sm[F_H2P + kc * 512 + (sub * 4 + 3) * 64 + c] = p3;
        #pragma unroll
        for (int i = 4; i < 12; ++i) sm[F_SW2 + tid + 512 * i] = rW[i];
    }
    __syncthreads();
    // ---- h2 reduce + sc2 fused ----
    {
        int n = tid >> 6, c = tid & 63;
        float hv = sm[F_H2P + n * 64 + c] + sm[F_H2P + 512 + n * 64 + c]
                 + sm[F_H2P + 1024 + n * 64 + c] + sm[F_H2P + 1536 + n * 64 + c];
        sm[F_H2 + n * 64 + c] = hv;
        float aS = hv * sm[F_G2AS + c], aD = hv * sm[F_G2AD + c];
        #pragma unroll
        for (int m = 32; m >= 1; m >>= 1) { aS += __shfl_xor(aS, m); aD += __shfl_xor(aD, m); }
        if (c == 0) { sm[F_SS2 + n] = aS; sm[F_SD2 + n] = aD; }
    }
    __syncthreads();
    // ---- stat2 (al2 inline) ----
    {
        #define AL2(e) ({ int _e = (e); \
            float _s = sm[F_SS2 + esrc[_e]] + sm[F_SD2 + edst[_e]] \
                     + sm[F_SML + SM_SE2 + ((_e < 16) ? _e : 16)]; \
            (_s > 0.f) ? _s : 0.2f * _s; })
        if (tid < 256) {
            int n = tid >> 5, g = tid & 31;
            float v = (g < 24 && edst[g] == n) ? AL2(g) : -1e30f;
            float mx = v;
            #pragma unroll
            for (int m = 16; m >= 1; m >>= 1) mx = fmaxf(mx, __shfl_xor(mx, m));
            float ex = expf(v - mx);
            #pragma unroll
            for (int m = 16; m >= 1; m >>= 1) ex += __shfl_xor(ex, m);
            if (g == 0) { sm[F_MX2 + n] = mx; sm[F_DN2 + n] = ex; }
        }
    }
    __syncthreads();
    if (tid < 24) {   // wt2 (al2 inline)
        int d = edst[tid];
        float al = AL2(tid);
        sm[F_WT2 + tid] = expf(al - sm[F_MX2 + d]) / (sm[F_DN2 + d] + 1e-16f);
        #undef AL2
    }
    __syncthreads();
    if (tid < 64) {   // A2
        int n = tid >> 3, s = tid & 7;
        float acc = 0.f;
        #pragma unroll
        for (int e = 0; e < 24; ++e)
            acc += (edst[e] == n && esrc[e] == s) ? sm[F_WT2 + e] : 0.f;
        sm[F_A2 + tid] = acc;
    }
    __syncthreads();
    {   // x2 = relu(A2 @ h2 + b2)
        int n = tid >> 6, c = tid & 63;
        float acc = 0.f;
        #pragma unroll
        for (int s = 0; s < 8; ++s) acc += sm[F_A2 + n * 8 + s] * sm[F_H2 + s * 64 + c];
        sm[F_X2 + n * 64 + c] = fmaxf(acc + sm[F_G2B + c], 0.f);
    }
    __syncthreads();
    if (tid < 64) {   // vm0 = mean_n(x2)
        float m = 0.f;
        #pragma unroll
        for (int n = 0; n < 8; ++n) m += sm[F_X2 + n * 64 + tid];
        sm[F_VM0 + tid] = m * 0.125f;
    }
    __syncthreads();   // ---- front dead ----

    // ---- dump remaining register-staged tail weights ----
    #pragma unroll
    for (int i = 0; i < 15; ++i) sm[tid + 512 * i] = rA[i];
    #pragma unroll
    for (int i = 0; i < 4; ++i) sm[F_SW2 + tid + 512 * i] = rW[i];
    __syncthreads();
    // ---- deconv: 120 outputs x 4-lane split ----
    if (tid < 480) {
        int o = tid >> 2, q = tid & 3;
        int t = o % 10, tau = (o / 10) % 3, rl = o / 30;
        float acc = 0.f;
        for (int i = q * 16; i < q * 16 + 16; ++i) {
            float vm = (tau == 0) ? sm[F_VM0 + i]
                     : (tau == 1) ? sm[F_SML + SM_VME + i]
                                  : sm[F_SML + SM_VME + 64 + i];
            acc += vm * sm[(tau * 64 + i) * 40 + rl * 10 + t];
        }
        acc += __shfl_xor(acc, 2); acc += __shfl_xor(acc, 1);
        if (q == 0) {
            int ch = (tau == 0) ? 0 : (tau + 1);
            sm[F_CIN + rl * 40 + ch * 10 + t] = acc + sm[F_SDB + tau * 4 + rl];
        }
    }
    __syncthreads();
    for (int o = tid; o < 1024; o += 512) {   // conv1 -> u @ sm[4096..5120)
        int rl = o >> 8, co = (o >> 3) & 31, p = o & 7;
        float acc = sm[F_SB1 + co];
        #pragma unroll
        for (int ci = 0; ci < 4; ++ci)
            #pragma unroll
            for (int k = 0; k < 3; ++k)
                acc += sm[F_CIN + rl * 40 + ci * 10 + p + k] * sm[F_SW1 + co * 12 + ci * 3 + k];
        sm[4096 + o] = acc;
    }
    __syncthreads();
    {   // conv2 + inline maxpool -> f @ sm[1024..1536)
        int rl = tid >> 7, m = tid & 127, co2 = m >> 1, p = m & 1;
        float acc = sm[F_SB2 + co2];
        for (int ci = 0; ci < 32; ++ci)
            #pragma unroll
            for (int k = 0; k < 3; ++k) {
                int u0 = 4096 + rl * 256 + ci * 8 + 2 * (p + k);
                acc += fmaxf(sm[u0], sm[u0 + 1]) * sm[F_SW2 + co2 * 96 + ci * 3 + k];
            }
        sm[1024 + rl * 128 + m] = acc;
    }
    __syncthreads();
    if (tid < 320) {  // fused (l1->l2) + relu, 8-lane split
        int o = tid >> 3, l = tid & 7;
        int rl = o / 10, t = o % 10;
        float acc = 0.f;
        for (int m = l * 16; m < l * 16 + 16; ++m)
            acc += sm[1024 + rl * 128 + m] * sm[F_SML + SM_WF + m * 10 + t];
        acc += __shfl_xor(acc, 4); acc += __shfl_xor(acc, 2); acc += __shfl_xor(acc, 1);
        if (l == 0)
            out[(r0 + rl) * 10 + t] = fmaxf(acc + sm[F_SML + SM_BF + t], 0.f);
    }
}

extern "C" void kernel_launch(void* const* d_in, const int* in_sizes, int n_in,
                              void* d_out, int out_size, void* d_ws, size_t ws_size,
                              hipStream_t stream)
{
    const float* xf    = (const float*)d_in[0];
    const float* xft   = (const float*)d_in[1];
    const float* ea    = (const float*)d_in[2];
    const float* c1w1  = (const float*)d_in[3];
    const float* c1b1  = (const float*)d_in[4];
    const float* c1w2  = (const float*)d_in[5];
    const float* c1b2  = (const float*)d_in[6];
    const float* g1lin = (const float*)d_in[7];
    const float* g1as  = (const float*)d_in[8];
    const float* g1ad  = (const float*)d_in[9];
    const float* g1le  = (const float*)d_in[10];
    const float* g1ae  = (const float*)d_in[11];
    const float* g1b   = (const float*)d_in[12];
    const float* g2lin = (const float*)d_in[13];
    const float* g2as  = (const float*)d_in[14];
    const float* g2ad  = (const float*)d_in[15];
    const float* g2le  = (const float*)d_in[16];
    const float* g2ae  = (const float*)d_in[17];
    const float* g2b   = (const float*)d_in[18];
    const float* mw1   = (const float*)d_in[19];
    const float* mb1   = (const float*)d_in[20];
    const float* mw2   = (const float*)d_in[21];
    const float* mb2   = (const float*)d_in[22];
    const float* d1w   = (const float*)d_in[23];
    const float* d1b   = (const float*)d_in[24];
    const float* d2w   = (const float*)d_in[25];
    const float* d2b   = (const float*)d_in[26];
    const float* d3w   = (const float*)d_in[27];
    const float* d3b   = (const float*)d_in[28];
    const float* c2w1  = (const float*)d_in[29];
    const float* c2b1  = (const float*)d_in[30];
    const float* c2w2  = (const float*)d_in[31];
    const float* c2b2  = (const float*)d_in[32];
    const float* l1w   = (const float*)d_in[33];
    const float* l1b   = (const float*)d_in[34];
    const float* l2w   = (const float*)d_in[35];
    const float* l2b   = (const float*)d_in[36];
    const int*   eidx  = (const int*)d_in[37];
    float* ws  = (float*)d_ws;
    float* out = (float*)d_out;

    hipLaunchKernelGGL(k1_pre, dim3(12), dim3(256), 0, stream,
        xf, xft, ea, c1w1, c1b1, c1w2, c1b2,
        g1lin, g1le, g1ae, mw1, mb1, mw2, mb2,
        g2le, g2ae, l1w, l1b, l2w, l2b, ws);
    hipLaunchKernelGGL(k2_main, dim3(16), dim3(512), 0, stream,
        xft, g1lin, g1as, g1ad, g1b,
        g2lin, g2as, g2ad, g2b, eidx,
        d1w, d1b, d2w, d2b, d3w, d3b,
        c2w1, c2b1, c2w2, c2b2, ws, out);
}